// Round 2
// baseline (2366.843 us; speedup 1.0000x reference)
//
#include <hip/hip_runtime.h>

// Problem constants
constexpr int BN   = 8;            // batch
constexpr int CIN  = 16;
constexpr int COUT = 32;
constexpr int S    = 24;           // spatial edge
constexpr int P    = S * S;        // 576 pixels per plane
constexpr int SP   = 26;           // padded edge
constexpr int PPAD = SP * SP;      // 676
constexpr int NPIX = P * P;        // 331776
constexpr float EPS = 1e-5f;

// Raw barrier: lgkmcnt(0) orders LDS ops cross-wave, but does NOT drain vmcnt,
// so register-staged global loads stay in flight across the barrier (unlike
// __syncthreads(), where the compiler emits s_waitcnt vmcnt(0)).
__device__ __forceinline__ void barrier_lgkm() {
    asm volatile("s_waitcnt lgkmcnt(0)" ::: "memory");
    __builtin_amdgcn_s_barrier();
    asm volatile("" ::: "memory");
}

__global__ void zero_stats_kernel(float* __restrict__ stats) {
    stats[threadIdx.x] = 0.f;
}

// Kernel A: conv over (hb,wb) plane + bias, write inter, accumulate GN stats.
// One block per (b, ha, wa), XCD-swizzled. 2-phase pipeline: stage ci+1 into
// registers while computing ci; raw barriers keep loads in flight.
// Weights are wave-uniform: fetched via scalar loads (readfirstlane-hoisted
// address), no LDS weight tile -> LDS ~2.7KB, occupancy 4 blocks/CU.
__global__ __launch_bounds__(256, 4)
void conv2_kernel(const float* __restrict__ x, const float* __restrict__ w2,
                  const float* __restrict__ b2, float* __restrict__ inter,
                  float* __restrict__ stats)
{
    __shared__ float xs[PPAD];               // one padded ci plane (borders stay 0)

    const int tid = threadIdx.x;
    const int bid = blockIdx.x;
    const int b   = bid & 7;                 // XCD swizzle: XCD k <- batch k
    const int haw = bid >> 3;

    for (int i = tid; i < PPAD; i += 256) xs[i] = 0.f;

    const int wave = tid >> 6, lane = tid & 63;
    const int co0 = wave * 8;
    const int co0u = __builtin_amdgcn_readfirstlane(co0);   // SGPR -> s_load path

    const float4 bA = *(const float4*)(b2 + co0);
    const float4 bB = *(const float4*)(b2 + co0 + 4);
    float4 accA[9], accB[9];
    int base[9];
#pragma unroll
    for (int j = 0; j < 9; ++j) {
        accA[j] = bA; accB[j] = bB;
        const int p = lane + 64 * j;
        const int hb = p / 24, wb = p - hb * 24;
        base[j] = hb * SP + wb;              // read xs[base + kh*26 + kw]
    }

    // staging: thread t<144 loads one float4 (pixels 4t..4t+3; rows are 24=4*6 wide)
    const bool act = tid < 144;
    int xoff = 0;
    if (act) {
        const int hb = tid / 6, wb0 = 4 * (tid % 6);
        xoff = (hb + 1) * SP + (wb0 + 1);
    }
    const float* xb0 = x + ((size_t)(b * CIN) * P + haw) * P;   // + ci*NPIX
    float4 stg = make_float4(0.f, 0.f, 0.f, 0.f);
    if (act) stg = *(const float4*)(xb0 + 4 * tid);

    barrier_lgkm();                          // xs zeros visible

#pragma unroll 1
    for (int ci = 0; ci < CIN; ++ci) {
        if (act) *(float4*)(xs + xoff) = stg;           // waits vmcnt for stg only
        if (ci + 1 < CIN && act)                        // issue next-ci loads now;
            stg = *(const float4*)(xb0 + (size_t)(ci + 1) * NPIX + 4 * tid);
        barrier_lgkm();                      // xs(ci) visible; loads stay in flight
        // wave-uniform weights, scalar loads: w2[co][ci][kh][kw], co stride 144
        const float* wci = w2 + (size_t)co0u * (CIN * 9) + ci * 9;
#pragma unroll
        for (int tap = 0; tap < 9; ++tap) {
            const int off = (tap / 3) * SP + (tap % 3);
            const float wk0 = wci[0 * 144 + tap];
            const float wk1 = wci[1 * 144 + tap];
            const float wk2 = wci[2 * 144 + tap];
            const float wk3 = wci[3 * 144 + tap];
            const float wk4 = wci[4 * 144 + tap];
            const float wk5 = wci[5 * 144 + tap];
            const float wk6 = wci[6 * 144 + tap];
            const float wk7 = wci[7 * 144 + tap];
#pragma unroll
            for (int j = 0; j < 9; ++j) {
                const float v = xs[base[j] + off];
                accA[j].x = fmaf(v, wk0, accA[j].x);
                accA[j].y = fmaf(v, wk1, accA[j].y);
                accA[j].z = fmaf(v, wk2, accA[j].z);
                accA[j].w = fmaf(v, wk3, accA[j].w);
                accB[j].x = fmaf(v, wk4, accB[j].x);
                accB[j].y = fmaf(v, wk5, accB[j].y);
                accB[j].z = fmaf(v, wk6, accB[j].z);
                accB[j].w = fmaf(v, wk7, accB[j].w);
            }
        }
        barrier_lgkm();                      // all reads done before next overwrite
    }

    // write inter + per-wave GN partial stats (post-bias values)
    float s = 0.f, ss = 0.f;
    float* dst = inter + (size_t)((b * COUT + co0) * P + haw) * P;
#pragma unroll
    for (int j = 0; j < 9; ++j) {
        const int p = lane + 64 * j;
        const float4 a = accA[j], c = accB[j];
        s  += a.x + a.y + a.z + a.w + c.x + c.y + c.z + c.w;
        ss += a.x*a.x + a.y*a.y + a.z*a.z + a.w*a.w
            + c.x*c.x + c.y*c.y + c.z*c.z + c.w*c.w;
        dst[0 * NPIX + p] = a.x; dst[1 * NPIX + p] = a.y;
        dst[2 * NPIX + p] = a.z; dst[3 * NPIX + p] = a.w;
        dst[4 * NPIX + p] = c.x; dst[5 * NPIX + p] = c.y;
        dst[6 * NPIX + p] = c.z; dst[7 * NPIX + p] = c.w;
    }
#pragma unroll
    for (int off = 32; off > 0; off >>= 1) {
        s  += __shfl_down(s, off);
        ss += __shfl_down(ss, off);
    }
    if (lane == 0) {
        atomicAdd(&stats[(b * 4 + wave) * 2 + 0], s);
        atomicAdd(&stats[(b * 4 + wave) * 2 + 1], ss);
    }
}

// Kernel B: finalize GN -> per (b,c) scale/shift
__global__ void gn_finalize_kernel(const float* __restrict__ stats,
                                   const float* __restrict__ gamma,
                                   const float* __restrict__ beta,
                                   float* __restrict__ scale,
                                   float* __restrict__ shift)
{
    const int t = threadIdx.x;           // 256 = 8b * 32c
    const int b = t >> 5, c = t & 31, g = c >> 3;
    const float sum = stats[(b * 4 + g) * 2 + 0];
    const float ssq = stats[(b * 4 + g) * 2 + 1];
    const float invN = 1.f / (8.f * (float)NPIX);
    const float mean = sum * invN;
    const float var  = ssq * invN - mean * mean;
    const float rstd = rsqrtf(var + EPS);
    const float sc   = gamma[c] * rstd;
    scale[t] = sc;
    shift[t] = beta[c] - mean * sc;
}

// Kernel C: conv over (ha,wa) plane; GN+ReLU applied at stage time.
// 9 input planes (1296 float4 chunks) register-staged per ci (<=6/thread),
// 2-phase pipelined with raw barriers. Weights wave-uniform via scalar loads
// -> LDS = pl only (20.7KB), target 4 blocks/CU.
__global__ __launch_bounds__(256, 4)
void conv1_kernel(const float* __restrict__ inter, const float* __restrict__ w1,
                  const float* __restrict__ b1, const float* __restrict__ scale,
                  const float* __restrict__ shift, float* __restrict__ out)
{
    __shared__ float pl[9 * P];              // 9 planes of one ci (20736 B)
    __shared__ float scs[COUT], shs[COUT];

    const int tid = threadIdx.x;
    const int bid = blockIdx.x;
    const int b   = bid & 7;                 // XCD swizzle
    const int haw = bid >> 3;
    const int ha  = haw / 24, wa = haw - ha * 24;

    if (tid < COUT) {
        scs[tid] = scale[b * 32 + tid];
        shs[tid] = shift[b * 32 + tid];
    }

    const int wave = tid >> 6, lane = tid & 63;
    const int co0 = wave * 8;
    const int co0u = __builtin_amdgcn_readfirstlane(co0);   // SGPR -> s_load path

    // per-thread stage chunks: float4 chunk c = tid + 256k, c < 1296.
    // chunk c -> plane q=c/144 (tap), offset within ci = plane_off*576 + 4*(c%144).
    // off[k] < 0  => stage zeros (border tap)
    int off[6];
#pragma unroll
    for (int k = 0; k < 6; ++k) {
        const int c = tid + 256 * k;
        off[k] = -1;
        if (c < 1296) {
            const int q = c / 144, r = c - q * 144;
            const int ha2 = ha + q / 3 - 1, wa2 = wa + (q % 3) - 1;
            if (((unsigned)ha2 < 24u) && ((unsigned)wa2 < 24u))
                off[k] = (ha2 * 24 + wa2) * P + 4 * r;
        }
    }

    const float* ib0 = inter + (size_t)(b * COUT) * NPIX;   // + ci*NPIX + off
    float4 stg[6];
#pragma unroll
    for (int k = 0; k < 6; ++k) {
        stg[k] = make_float4(0.f, 0.f, 0.f, 0.f);
        if (off[k] >= 0) stg[k] = *(const float4*)(ib0 + off[k]);
    }

    const float4 bA = *(const float4*)(b1 + co0);
    const float4 bB = *(const float4*)(b1 + co0 + 4);
    float4 accA[9], accB[9];
#pragma unroll
    for (int j = 0; j < 9; ++j) { accA[j] = bA; accB[j] = bB; }

    barrier_lgkm();                          // scs/shs visible

#pragma unroll 1
    for (int ci = 0; ci < COUT; ++ci) {
        const float sc = scs[ci], sh = shs[ci];
        // stage regs -> pl, fusing GN + ReLU; border chunks -> 0
#pragma unroll
        for (int k = 0; k < 6; ++k) {
            const int c = tid + 256 * k;
            if (c < 1296) {
                const float4 v = stg[k];
                float4 w;
                w.x = fmaxf(fmaf(v.x, sc, sh), 0.f);
                w.y = fmaxf(fmaf(v.y, sc, sh), 0.f);
                w.z = fmaxf(fmaf(v.z, sc, sh), 0.f);
                w.w = fmaxf(fmaf(v.w, sc, sh), 0.f);
                if (off[k] < 0) w = make_float4(0.f, 0.f, 0.f, 0.f);
                *(float4*)(pl + 4 * c) = w;
            }
        }
        // issue next-ci loads; they ride across the raw barriers under compute
        if (ci + 1 < COUT) {
            const float* ib = ib0 + (size_t)(ci + 1) * NPIX;
#pragma unroll
            for (int k = 0; k < 6; ++k)
                if (off[k] >= 0) stg[k] = *(const float4*)(ib + off[k]);
        }
        barrier_lgkm();                      // pl(ci) visible to all waves
        // wave-uniform weights, scalar loads: w1[co][ci][kh][kw], co stride 288
        const float* wci = w1 + (size_t)co0u * (COUT * 9) + ci * 9;
#pragma unroll
        for (int tap = 0; tap < 9; ++tap) {
            const float wk0 = wci[0 * 288 + tap];
            const float wk1 = wci[1 * 288 + tap];
            const float wk2 = wci[2 * 288 + tap];
            const float wk3 = wci[3 * 288 + tap];
            const float wk4 = wci[4 * 288 + tap];
            const float wk5 = wci[5 * 288 + tap];
            const float wk6 = wci[6 * 288 + tap];
            const float wk7 = wci[7 * 288 + tap];
#pragma unroll
            for (int j = 0; j < 9; ++j) {
                const float v = pl[tap * P + lane + 64 * j];
                accA[j].x = fmaf(v, wk0, accA[j].x);
                accA[j].y = fmaf(v, wk1, accA[j].y);
                accA[j].z = fmaf(v, wk2, accA[j].z);
                accA[j].w = fmaf(v, wk3, accA[j].w);
                accB[j].x = fmaf(v, wk4, accB[j].x);
                accB[j].y = fmaf(v, wk5, accB[j].y);
                accB[j].z = fmaf(v, wk6, accB[j].z);
                accB[j].w = fmaf(v, wk7, accB[j].w);
            }
        }
        barrier_lgkm();                      // all reads done before next overwrite
    }

    float* dst = out + (size_t)((b * COUT + co0) * P + haw) * P;
#pragma unroll
    for (int j = 0; j < 9; ++j) {
        const int p = lane + 64 * j;
        dst[0 * NPIX + p] = accA[j].x; dst[1 * NPIX + p] = accA[j].y;
        dst[2 * NPIX + p] = accA[j].z; dst[3 * NPIX + p] = accA[j].w;
        dst[4 * NPIX + p] = accB[j].x; dst[5 * NPIX + p] = accB[j].y;
        dst[6 * NPIX + p] = accB[j].z; dst[7 * NPIX + p] = accB[j].w;
    }
}

extern "C" void kernel_launch(void* const* d_in, const int* in_sizes, int n_in,
                              void* d_out, int out_size, void* d_ws, size_t ws_size,
                              hipStream_t stream) {
    const float* x       = (const float*)d_in[0];
    const float* conv1_w = (const float*)d_in[1];
    const float* conv1_b = (const float*)d_in[2];
    const float* conv2_w = (const float*)d_in[3];
    const float* conv2_b = (const float*)d_in[4];
    const float* gamma   = (const float*)d_in[5];
    const float* beta    = (const float*)d_in[6];
    float* out = (float*)d_out;

    float* wsf   = (float*)d_ws;
    float* stats = wsf;            // 64 floats
    float* scale = wsf + 64;       // 256 floats
    float* shift = wsf + 320;      // 256 floats
    float* inter = wsf + 1024;     // 84,934,656 floats

    zero_stats_kernel<<<1, 64, 0, stream>>>(stats);
    conv2_kernel<<<BN * P, 256, 0, stream>>>(x, conv2_w, conv2_b, inter, stats);
    gn_finalize_kernel<<<1, 256, 0, stream>>>(stats, gamma, beta, scale, shift);
    conv1_kernel<<<BN * P, 256, 0, stream>>>(inter, conv1_w, conv1_b,
                                             scale, shift, out);
}

// Round 3
// 1228.152 us; speedup vs baseline: 1.9272x; 1.9272x over previous
//
#include <hip/hip_runtime.h>

// Problem constants
constexpr int BN   = 8;            // batch
constexpr int CIN  = 16;
constexpr int COUT = 32;
constexpr int S    = 24;           // spatial edge
constexpr int P    = S * S;        // 576 pixels per plane
constexpr int SP   = 26;           // padded edge
constexpr int PPAD = SP * SP;      // 676
constexpr int NPIX = P * P;        // 331776
constexpr float EPS = 1e-5f;

// Raw barrier: lgkmcnt(0) orders LDS ops cross-wave, but does NOT drain vmcnt,
// so register-staged global loads stay in flight across the barrier (unlike
// __syncthreads(), where the compiler emits s_waitcnt vmcnt(0)).
__device__ __forceinline__ void barrier_lgkm() {
    asm volatile("s_waitcnt lgkmcnt(0)" ::: "memory");
    __builtin_amdgcn_s_barrier();
    asm volatile("" ::: "memory");
}

__global__ void zero_stats_kernel(float* __restrict__ stats) {
    stats[threadIdx.x] = 0.f;
}

// Kernel A: conv over (hb,wb) plane + bias, write inter, accumulate GN stats.
// One block per (b, ha, wa), XCD-swizzled. 2-phase pipeline: stage ci+1 into
// registers while computing ci; raw barriers keep loads in flight.
// Weights are wave-uniform: fetched via scalar loads (readfirstlane-hoisted
// address), no LDS weight tile. launch_bounds(256,3): VGPR cap 168 -> no
// spills (natural ~150), 3 blocks/CU.
__global__ __launch_bounds__(256, 3)
void conv2_kernel(const float* __restrict__ x, const float* __restrict__ w2,
                  const float* __restrict__ b2, float* __restrict__ inter,
                  float* __restrict__ stats)
{
    __shared__ float xs[PPAD];               // one padded ci plane (borders stay 0)

    const int tid = threadIdx.x;
    const int bid = blockIdx.x;
    const int b   = bid & 7;                 // XCD swizzle: XCD k <- batch k
    const int haw = bid >> 3;

    for (int i = tid; i < PPAD; i += 256) xs[i] = 0.f;

    const int wave = tid >> 6, lane = tid & 63;
    const int co0 = wave * 8;
    const int co0u = __builtin_amdgcn_readfirstlane(co0);   // SGPR -> s_load path

    const float4 bA = *(const float4*)(b2 + co0);
    const float4 bB = *(const float4*)(b2 + co0 + 4);
    float4 accA[9], accB[9];
    int base[9];
#pragma unroll
    for (int j = 0; j < 9; ++j) {
        accA[j] = bA; accB[j] = bB;
        const int p = lane + 64 * j;
        const int hb = p / 24, wb = p - hb * 24;
        base[j] = hb * SP + wb;              // read xs[base + kh*26 + kw]
    }

    // staging: thread t<144 loads one float4 (pixels 4t..4t+3; rows are 24=4*6 wide)
    const bool act = tid < 144;
    int xoff = 0;
    if (act) {
        const int hb = tid / 6, wb0 = 4 * (tid % 6);
        xoff = (hb + 1) * SP + (wb0 + 1);
    }
    const float* xb0 = x + ((size_t)(b * CIN) * P + haw) * P;   // + ci*NPIX
    float4 stg = make_float4(0.f, 0.f, 0.f, 0.f);
    if (act) stg = *(const float4*)(xb0 + 4 * tid);

    barrier_lgkm();                          // xs zeros visible

#pragma unroll 1
    for (int ci = 0; ci < CIN; ++ci) {
        if (act) *(float4*)(xs + xoff) = stg;           // waits vmcnt for stg only
        if (ci + 1 < CIN && act)                        // issue next-ci loads now;
            stg = *(const float4*)(xb0 + (size_t)(ci + 1) * NPIX + 4 * tid);
        barrier_lgkm();                      // xs(ci) visible; loads stay in flight
        // wave-uniform weights, scalar loads: w2[co][ci][kh][kw], co stride 144
        const float* wci = w2 + (size_t)co0u * (CIN * 9) + ci * 9;
#pragma unroll
        for (int tap = 0; tap < 9; ++tap) {
            const int off = (tap / 3) * SP + (tap % 3);
            const float wk0 = wci[0 * 144 + tap];
            const float wk1 = wci[1 * 144 + tap];
            const float wk2 = wci[2 * 144 + tap];
            const float wk3 = wci[3 * 144 + tap];
            const float wk4 = wci[4 * 144 + tap];
            const float wk5 = wci[5 * 144 + tap];
            const float wk6 = wci[6 * 144 + tap];
            const float wk7 = wci[7 * 144 + tap];
#pragma unroll
            for (int j = 0; j < 9; ++j) {
                const float v = xs[base[j] + off];
                accA[j].x = fmaf(v, wk0, accA[j].x);
                accA[j].y = fmaf(v, wk1, accA[j].y);
                accA[j].z = fmaf(v, wk2, accA[j].z);
                accA[j].w = fmaf(v, wk3, accA[j].w);
                accB[j].x = fmaf(v, wk4, accB[j].x);
                accB[j].y = fmaf(v, wk5, accB[j].y);
                accB[j].z = fmaf(v, wk6, accB[j].z);
                accB[j].w = fmaf(v, wk7, accB[j].w);
            }
        }
        barrier_lgkm();                      // all reads done before next overwrite
    }

    // write inter + per-wave GN partial stats (post-bias values)
    float s = 0.f, ss = 0.f;
    float* dst = inter + (size_t)((b * COUT + co0) * P + haw) * P;
#pragma unroll
    for (int j = 0; j < 9; ++j) {
        const int p = lane + 64 * j;
        const float4 a = accA[j], c = accB[j];
        s  += a.x + a.y + a.z + a.w + c.x + c.y + c.z + c.w;
        ss += a.x*a.x + a.y*a.y + a.z*a.z + a.w*a.w
            + c.x*c.x + c.y*c.y + c.z*c.z + c.w*c.w;
        dst[0 * NPIX + p] = a.x; dst[1 * NPIX + p] = a.y;
        dst[2 * NPIX + p] = a.z; dst[3 * NPIX + p] = a.w;
        dst[4 * NPIX + p] = c.x; dst[5 * NPIX + p] = c.y;
        dst[6 * NPIX + p] = c.z; dst[7 * NPIX + p] = c.w;
    }
#pragma unroll
    for (int off = 32; off > 0; off >>= 1) {
        s  += __shfl_down(s, off);
        ss += __shfl_down(ss, off);
    }
    if (lane == 0) {
        atomicAdd(&stats[(b * 4 + wave) * 2 + 0], s);
        atomicAdd(&stats[(b * 4 + wave) * 2 + 1], ss);
    }
}

// Kernel B: finalize GN -> per (b,c) scale/shift
__global__ void gn_finalize_kernel(const float* __restrict__ stats,
                                   const float* __restrict__ gamma,
                                   const float* __restrict__ beta,
                                   float* __restrict__ scale,
                                   float* __restrict__ shift)
{
    const int t = threadIdx.x;           // 256 = 8b * 32c
    const int b = t >> 5, c = t & 31, g = c >> 3;
    const float sum = stats[(b * 4 + g) * 2 + 0];
    const float ssq = stats[(b * 4 + g) * 2 + 1];
    const float invN = 1.f / (8.f * (float)NPIX);
    const float mean = sum * invN;
    const float var  = ssq * invN - mean * mean;
    const float rstd = rsqrtf(var + EPS);
    const float sc   = gamma[c] * rstd;
    scale[t] = sc;
    shift[t] = beta[c] - mean * sc;
}

// Kernel C: conv over (ha,wa) plane; GN+ReLU applied at stage time.
// 9 input planes (1296 float4 chunks) register-staged per ci (<=6/thread),
// 2-phase pipelined with raw barriers. Weights wave-uniform via scalar loads
// -> LDS = pl only (20.7KB). launch_bounds(256,3): no spills, 3 blocks/CU.
__global__ __launch_bounds__(256, 3)
void conv1_kernel(const float* __restrict__ inter, const float* __restrict__ w1,
                  const float* __restrict__ b1, const float* __restrict__ scale,
                  const float* __restrict__ shift, float* __restrict__ out)
{
    __shared__ float pl[9 * P];              // 9 planes of one ci (20736 B)
    __shared__ float scs[COUT], shs[COUT];

    const int tid = threadIdx.x;
    const int bid = blockIdx.x;
    const int b   = bid & 7;                 // XCD swizzle
    const int haw = bid >> 3;
    const int ha  = haw / 24, wa = haw - ha * 24;

    if (tid < COUT) {
        scs[tid] = scale[b * 32 + tid];
        shs[tid] = shift[b * 32 + tid];
    }

    const int wave = tid >> 6, lane = tid & 63;
    const int co0 = wave * 8;
    const int co0u = __builtin_amdgcn_readfirstlane(co0);   // SGPR -> s_load path

    // per-thread stage chunks: float4 chunk c = tid + 256k, c < 1296.
    // chunk c -> plane q=c/144 (tap), offset within ci = plane_off*576 + 4*(c%144).
    // off[k] < 0  => stage zeros (border tap)
    int off[6];
#pragma unroll
    for (int k = 0; k < 6; ++k) {
        const int c = tid + 256 * k;
        off[k] = -1;
        if (c < 1296) {
            const int q = c / 144, r = c - q * 144;
            const int ha2 = ha + q / 3 - 1, wa2 = wa + (q % 3) - 1;
            if (((unsigned)ha2 < 24u) && ((unsigned)wa2 < 24u))
                off[k] = (ha2 * 24 + wa2) * P + 4 * r;
        }
    }

    const float* ib0 = inter + (size_t)(b * COUT) * NPIX;   // + ci*NPIX + off
    float4 stg[6];
#pragma unroll
    for (int k = 0; k < 6; ++k) {
        stg[k] = make_float4(0.f, 0.f, 0.f, 0.f);
        if (off[k] >= 0) stg[k] = *(const float4*)(ib0 + off[k]);
    }

    const float4 bA = *(const float4*)(b1 + co0);
    const float4 bB = *(const float4*)(b1 + co0 + 4);
    float4 accA[9], accB[9];
#pragma unroll
    for (int j = 0; j < 9; ++j) { accA[j] = bA; accB[j] = bB; }

    barrier_lgkm();                          // scs/shs visible

#pragma unroll 1
    for (int ci = 0; ci < COUT; ++ci) {
        const float sc = scs[ci], sh = shs[ci];
        // stage regs -> pl, fusing GN + ReLU; border chunks -> 0
#pragma unroll
        for (int k = 0; k < 6; ++k) {
            const int c = tid + 256 * k;
            if (c < 1296) {
                const float4 v = stg[k];
                float4 w;
                w.x = fmaxf(fmaf(v.x, sc, sh), 0.f);
                w.y = fmaxf(fmaf(v.y, sc, sh), 0.f);
                w.z = fmaxf(fmaf(v.z, sc, sh), 0.f);
                w.w = fmaxf(fmaf(v.w, sc, sh), 0.f);
                if (off[k] < 0) w = make_float4(0.f, 0.f, 0.f, 0.f);
                *(float4*)(pl + 4 * c) = w;
            }
        }
        // issue next-ci loads; they ride across the raw barriers under compute
        if (ci + 1 < COUT) {
            const float* ib = ib0 + (size_t)(ci + 1) * NPIX;
#pragma unroll
            for (int k = 0; k < 6; ++k)
                if (off[k] >= 0) stg[k] = *(const float4*)(ib + off[k]);
        }
        barrier_lgkm();                      // pl(ci) visible to all waves
        // wave-uniform weights, scalar loads: w1[co][ci][kh][kw], co stride 288
        const float* wci = w1 + (size_t)co0u * (COUT * 9) + ci * 9;
#pragma unroll
        for (int tap = 0; tap < 9; ++tap) {
            const float wk0 = wci[0 * 288 + tap];
            const float wk1 = wci[1 * 288 + tap];
            const float wk2 = wci[2 * 288 + tap];
            const float wk3 = wci[3 * 288 + tap];
            const float wk4 = wci[4 * 288 + tap];
            const float wk5 = wci[5 * 288 + tap];
            const float wk6 = wci[6 * 288 + tap];
            const float wk7 = wci[7 * 288 + tap];
#pragma unroll
            for (int j = 0; j < 9; ++j) {
                const float v = pl[tap * P + lane + 64 * j];
                accA[j].x = fmaf(v, wk0, accA[j].x);
                accA[j].y = fmaf(v, wk1, accA[j].y);
                accA[j].z = fmaf(v, wk2, accA[j].z);
                accA[j].w = fmaf(v, wk3, accA[j].w);
                accB[j].x = fmaf(v, wk4, accB[j].x);
                accB[j].y = fmaf(v, wk5, accB[j].y);
                accB[j].z = fmaf(v, wk6, accB[j].z);
                accB[j].w = fmaf(v, wk7, accB[j].w);
            }
        }
        barrier_lgkm();                      // all reads done before next overwrite
    }

    float* dst = out + (size_t)((b * COUT + co0) * P + haw) * P;
#pragma unroll
    for (int j = 0; j < 9; ++j) {
        const int p = lane + 64 * j;
        dst[0 * NPIX + p] = accA[j].x; dst[1 * NPIX + p] = accA[j].y;
        dst[2 * NPIX + p] = accA[j].z; dst[3 * NPIX + p] = accA[j].w;
        dst[4 * NPIX + p] = accB[j].x; dst[5 * NPIX + p] = accB[j].y;
        dst[6 * NPIX + p] = accB[j].z; dst[7 * NPIX + p] = accB[j].w;
    }
}

extern "C" void kernel_launch(void* const* d_in, const int* in_sizes, int n_in,
                              void* d_out, int out_size, void* d_ws, size_t ws_size,
                              hipStream_t stream) {
    const float* x       = (const float*)d_in[0];
    const float* conv1_w = (const float*)d_in[1];
    const float* conv1_b = (const float*)d_in[2];
    const float* conv2_w = (const float*)d_in[3];
    const float* conv2_b = (const float*)d_in[4];
    const float* gamma   = (const float*)d_in[5];
    const float* beta    = (const float*)d_in[6];
    float* out = (float*)d_out;

    float* wsf   = (float*)d_ws;
    float* stats = wsf;            // 64 floats
    float* scale = wsf + 64;       // 256 floats
    float* shift = wsf + 320;      // 256 floats
    float* inter = wsf + 1024;     // 84,934,656 floats

    zero_stats_kernel<<<1, 64, 0, stream>>>(stats);
    conv2_kernel<<<BN * P, 256, 0, stream>>>(x, conv2_w, conv2_b, inter, stats);
    gn_finalize_kernel<<<1, 256, 0, stream>>>(stats, gamma, beta, scale, shift);
    conv1_kernel<<<BN * P, 256, 0, stream>>>(inter, conv1_w, conv1_b,
                                             scale, shift, out);
}